// Round 5
// baseline (92.147 us; speedup 1.0000x reference)
//
#include <hip/hip_runtime.h>
#include <math.h>

#define N_PTS 2048
#define N_SETS 16          // B*S = 2*8
#define B_VAL 2.0f
#define BLOCK 256
#define SEGS 32
#define CPS (N_PTS / SEGS)   // 64 candidates per segment
#define QPT 8                // queries per thread (2048 / 256)

__device__ __forceinline__ float sl1(float d) {
    d = fabsf(d);
    return d < 1.0f ? 0.5f * d * d : d - 0.5f;
}

// grid = (SEGS, N_SETS, 2). Each block: ALL 2048 queries of one (set,dir)
// against a 64-candidate segment staged in LDS. Thread t handles queries
// t + 256*j. 1024 blocks = 4 blocks/CU = 4 waves/SIMD for latency hiding.
// Per-seg (dist, idx) written contention-free to ws[sd][seg][q].
__global__ __launch_bounds__(BLOCK) void chamfer_partial(
    const float* __restrict__ X, const float* __restrict__ T,
    float2* __restrict__ ws, float* __restrict__ out)
{
    const int seg = blockIdx.x;
    const int set = blockIdx.y;
    const int dir = blockIdx.z;
    const int tid = threadIdx.x;

    if (seg == 0 && set == 0 && dir == 0 && tid == 0) {
        out[0] = 0.0f;  // consumed by finalize (stream-ordered)
        out[1] = 0.0f;
    }

    const float* psrc = (dir == 0) ? (X + (size_t)set * N_PTS * 3)
                                   : (T + (size_t)set * N_PTS * 3);
    const float* csrc = (dir == 0) ? (T + (size_t)set * N_PTS * 3)
                                   : (X + (size_t)set * N_PTS * 3);

    // Stage this segment's candidates as (x,y,z,|c|^2) float4 in LDS.
    __shared__ float4 cand[CPS];
    if (tid < CPS) {
        const int g = seg * CPS + tid;
        float cx = csrc[g * 3 + 0];
        float cy = csrc[g * 3 + 1];
        float cz = csrc[g * 3 + 2];
        cand[tid] = make_float4(cx, cy, cz, cx * cx + cy * cy + cz * cz);
    }
    __syncthreads();

    // My 8 query points; precompute -2*coord (|p|^2 dropped: constant
    // shift per query, argmin-invariant).
    float ax[QPT], ay[QPT], az[QPT];
    float best[QPT];
    int   bidx[QPT];
#pragma unroll
    for (int j = 0; j < QPT; ++j) {
        const int q = tid + BLOCK * j;
        ax[j] = -2.0f * psrc[q * 3 + 0];
        ay[j] = -2.0f * psrc[q * 3 + 1];
        az[j] = -2.0f * psrc[q * 3 + 2];
        best[j] = INFINITY;
        bidx[j] = 0;
    }

    // One broadcast LDS read amortized over 8 queries (48 VALU / ds_read).
    // Strict <: first occurrence wins (ascending m) == jnp.argmin tiebreak.
#pragma unroll 4
    for (int m = 0; m < CPS; ++m) {
        float4 c = cand[m];
#pragma unroll
        for (int j = 0; j < QPT; ++j) {
            float d = fmaf(ax[j], c.x, fmaf(ay[j], c.y, fmaf(az[j], c.z, c.w)));
            if (d < best[j]) { best[j] = d; bidx[j] = m; }
        }
    }

    // Contention-free coalesced stores: ws[(sd*SEGS+seg)*2048 + q].
    float2* wq = ws + ((size_t)((set * 2 + dir) * SEGS + seg) << 11);
#pragma unroll
    for (int j = 0; j < QPT; ++j) {
        const int q = tid + BLOCK * j;
        float2 v;
        v.x = best[j];
        v.y = __uint_as_float((unsigned int)(seg * CPS + bidx[j]));
        wq[q] = v;
    }
}

// grid = (N_PTS/BLOCK + 1, N_SETS, 2).
// chunk < 8 : merge 32 seg-results per query, smooth-L1, weighted reduce.
// chunk == 8, dir == 0 : centroid loss for this set. (dir==1: idle)
__global__ __launch_bounds__(BLOCK) void finalize_kernel(
    const float* __restrict__ X, const float* __restrict__ T,
    const float* __restrict__ W, const float2* __restrict__ ws,
    float* __restrict__ out)
{
    const int chunk = blockIdx.x;
    const int set   = blockIdx.y;
    const int dir   = blockIdx.z;
    const int tid   = threadIdx.x;

    if (chunk == N_PTS / BLOCK) {
        // ---- centroid path ----
        if (dir != 0) return;
        const float* xb = X + (size_t)set * N_PTS * 3;
        const float* tb = T + (size_t)set * N_PTS * 3;
        float acc[6] = {0, 0, 0, 0, 0, 0};
        for (int i = tid; i < N_PTS; i += BLOCK) {
            acc[0] += xb[i * 3 + 0];
            acc[1] += xb[i * 3 + 1];
            acc[2] += xb[i * 3 + 2];
            acc[3] += tb[i * 3 + 0];
            acc[4] += tb[i * 3 + 1];
            acc[5] += tb[i * 3 + 2];
        }
#pragma unroll
        for (int k = 0; k < 6; ++k)
            for (int off = 32; off > 0; off >>= 1)
                acc[k] += __shfl_down(acc[k], off, 64);
        __shared__ float red[4][6];
        if ((tid & 63) == 0)
#pragma unroll
            for (int k = 0; k < 6; ++k) red[tid >> 6][k] = acc[k];
        __syncthreads();
        if (tid == 0) {
            const float inv = 1.0f / (float)N_PTS;
            float l = 0.0f;
#pragma unroll
            for (int k = 0; k < 3; ++k) {
                float a = (red[0][k] + red[1][k] + red[2][k] + red[3][k]) * inv;
                float b = (red[0][k+3] + red[1][k+3] + red[2][k+3] + red[3][k+3]) * inv;
                l += sl1(a - b);
            }
            atomicAdd(&out[1], l * (1.0f / (B_VAL * 3.0f)));
        }
        return;
    }

    // ---- chamfer merge path ----
    const int n = chunk * BLOCK + tid;
    const float* psrc = (dir == 0) ? (X + (size_t)set * N_PTS * 3)
                                   : (T + (size_t)set * N_PTS * 3);
    const float* csrc = (dir == 0) ? (T + (size_t)set * N_PTS * 3)
                                   : (X + (size_t)set * N_PTS * 3);

    // Merge per-seg partials; ascending seg + strict < == lowest-index tiebreak.
    const float2* wq = ws + ((size_t)((set * 2 + dir) * SEGS) << 11);
    float bestd = INFINITY;
    unsigned int idx = 0;
#pragma unroll
    for (int s = 0; s < SEGS; ++s) {
        float2 v = wq[((size_t)s << 11) + n];
        if (v.x < bestd) { bestd = v.x; idx = __float_as_uint(v.y); }
    }

    float s = sl1(psrc[n * 3 + 0] - csrc[idx * 3 + 0])
            + sl1(psrc[n * 3 + 1] - csrc[idx * 3 + 1])
            + sl1(psrc[n * 3 + 2] - csrc[idx * 3 + 2]);

    __shared__ float wpart[4];
    for (int off = 32; off > 0; off >>= 1)
        s += __shfl_down(s, off, 64);
    if ((tid & 63) == 0) wpart[tid >> 6] = s;
    __syncthreads();
    if (tid == 0) {
        float tot = wpart[0] + wpart[1] + wpart[2] + wpart[3];
        atomicAdd(&out[0], W[set] * tot * (1.0f / (N_PTS * 3.0f * B_VAL)));
    }
}

extern "C" void kernel_launch(void* const* d_in, const int* in_sizes, int n_in,
                              void* d_out, int out_size, void* d_ws, size_t ws_size,
                              hipStream_t stream) {
    const float* X = (const float*)d_in[0];
    const float* T = (const float*)d_in[1];
    const float* W = (const float*)d_in[2];
    float* out = (float*)d_out;
    float2* ws = (float2*)d_ws;   // 32 * 32 * 2048 float2 = 16 MB

    chamfer_partial<<<dim3(SEGS, N_SETS, 2), BLOCK, 0, stream>>>(X, T, ws, out);
    finalize_kernel<<<dim3(N_PTS / BLOCK + 1, N_SETS, 2), BLOCK, 0, stream>>>(X, T, W, ws, out);
}

// Round 6
// 85.746 us; speedup vs baseline: 1.0747x; 1.0747x over previous
//
#include <hip/hip_runtime.h>
#include <math.h>

#define N_PTS 2048
#define N_SETS 16          // B*S = 2*8
#define B_VAL 2.0f
#define BLOCK 256
#define SEGS 16
#define CPS (N_PTS / SEGS)   // 128 candidates per segment
#define QPT 8                // queries per thread (2048 / 256)

__device__ __forceinline__ float sl1(float d) {
    d = fabsf(d);
    return d < 1.0f ? 0.5f * d * d : d - 0.5f;
}

// grid = (SEGS, N_SETS, 2). Each block: ALL 2048 queries of one (set,dir)
// against a 128-candidate segment. Thread t handles queries t+256*j.
// Per-seg (dist, idx) written contention-free to ws[sd][seg][q].
// SEGS=16 is measured-optimal: SEGS=32 doubles ws traffic (+merge work) for
// no VALU gain (R5: +5.6us); packed-fp32 pairs regressed (R4: +2.4us).
__global__ __launch_bounds__(BLOCK) void chamfer_partial(
    const float* __restrict__ X, const float* __restrict__ T,
    float2* __restrict__ ws, float* __restrict__ out)
{
    const int seg = blockIdx.x;
    const int set = blockIdx.y;
    const int dir = blockIdx.z;
    const int tid = threadIdx.x;

    if (seg == 0 && set == 0 && dir == 0 && tid == 0) {
        out[0] = 0.0f;  // consumed by finalize (stream-ordered)
        out[1] = 0.0f;
    }

    const float* psrc = (dir == 0) ? (X + (size_t)set * N_PTS * 3)
                                   : (T + (size_t)set * N_PTS * 3);
    const float* csrc = (dir == 0) ? (T + (size_t)set * N_PTS * 3)
                                   : (X + (size_t)set * N_PTS * 3);

    // Stage this segment's candidates as (x,y,z,|c|^2) float4 in LDS.
    __shared__ float4 cand[CPS];
    if (tid < CPS) {
        const int g = seg * CPS + tid;
        float cx = csrc[g * 3 + 0];
        float cy = csrc[g * 3 + 1];
        float cz = csrc[g * 3 + 2];
        cand[tid] = make_float4(cx, cy, cz, cx * cx + cy * cy + cz * cz);
    }
    __syncthreads();

    // My 8 query points; precompute -2*coord (|p|^2 dropped: constant
    // shift per query, argmin-invariant).
    float ax[QPT], ay[QPT], az[QPT];
    float best[QPT];
    int   bidx[QPT];
#pragma unroll
    for (int j = 0; j < QPT; ++j) {
        const int q = tid + BLOCK * j;
        ax[j] = -2.0f * psrc[q * 3 + 0];
        ay[j] = -2.0f * psrc[q * 3 + 1];
        az[j] = -2.0f * psrc[q * 3 + 2];
        best[j] = INFINITY;
        bidx[j] = 0;
    }

    // One broadcast LDS read amortized over 8 queries (48 VALU / ds_read).
    // Strict <: first occurrence wins (ascending m) == jnp.argmin tiebreak.
    // Floor: 6 VALU/pair (3 fma + cmp + 2 cndmask) -> ~10 us GPU-wide.
#pragma unroll 4
    for (int m = 0; m < CPS; ++m) {
        float4 c = cand[m];
#pragma unroll
        for (int j = 0; j < QPT; ++j) {
            float d = fmaf(ax[j], c.x, fmaf(ay[j], c.y, fmaf(az[j], c.z, c.w)));
            if (d < best[j]) { best[j] = d; bidx[j] = m; }
        }
    }

    // Contention-free coalesced stores: ws[(sd*SEGS+seg)*2048 + q].
    float2* wq = ws + ((size_t)((set * 2 + dir) * SEGS + seg) << 11);
#pragma unroll
    for (int j = 0; j < QPT; ++j) {
        const int q = tid + BLOCK * j;
        float2 v;
        v.x = best[j];
        v.y = __uint_as_float((unsigned int)(seg * CPS + bidx[j]));
        wq[q] = v;
    }
}

// grid = (N_PTS/BLOCK + 1, N_SETS, 2).
// chunk < 8 : merge 16 seg-results per query, smooth-L1, weighted reduce.
// chunk == 8, dir == 0 : centroid loss for this set. (dir==1: idle)
__global__ __launch_bounds__(BLOCK) void finalize_kernel(
    const float* __restrict__ X, const float* __restrict__ T,
    const float* __restrict__ W, const float2* __restrict__ ws,
    float* __restrict__ out)
{
    const int chunk = blockIdx.x;
    const int set   = blockIdx.y;
    const int dir   = blockIdx.z;
    const int tid   = threadIdx.x;

    if (chunk == N_PTS / BLOCK) {
        // ---- centroid path ----
        if (dir != 0) return;
        const float* xb = X + (size_t)set * N_PTS * 3;
        const float* tb = T + (size_t)set * N_PTS * 3;
        float acc[6] = {0, 0, 0, 0, 0, 0};
        for (int i = tid; i < N_PTS; i += BLOCK) {
            acc[0] += xb[i * 3 + 0];
            acc[1] += xb[i * 3 + 1];
            acc[2] += xb[i * 3 + 2];
            acc[3] += tb[i * 3 + 0];
            acc[4] += tb[i * 3 + 1];
            acc[5] += tb[i * 3 + 2];
        }
#pragma unroll
        for (int k = 0; k < 6; ++k)
            for (int off = 32; off > 0; off >>= 1)
                acc[k] += __shfl_down(acc[k], off, 64);
        __shared__ float red[4][6];
        if ((tid & 63) == 0)
#pragma unroll
            for (int k = 0; k < 6; ++k) red[tid >> 6][k] = acc[k];
        __syncthreads();
        if (tid == 0) {
            const float inv = 1.0f / (float)N_PTS;
            float l = 0.0f;
#pragma unroll
            for (int k = 0; k < 3; ++k) {
                float a = (red[0][k] + red[1][k] + red[2][k] + red[3][k]) * inv;
                float b = (red[0][k+3] + red[1][k+3] + red[2][k+3] + red[3][k+3]) * inv;
                l += sl1(a - b);
            }
            atomicAdd(&out[1], l * (1.0f / (B_VAL * 3.0f)));
        }
        return;
    }

    // ---- chamfer merge path ----
    const int n = chunk * BLOCK + tid;
    const float* psrc = (dir == 0) ? (X + (size_t)set * N_PTS * 3)
                                   : (T + (size_t)set * N_PTS * 3);
    const float* csrc = (dir == 0) ? (T + (size_t)set * N_PTS * 3)
                                   : (X + (size_t)set * N_PTS * 3);

    // Merge per-seg partials; ascending seg + strict < == lowest-index tiebreak.
    const float2* wq = ws + ((size_t)((set * 2 + dir) * SEGS) << 11);
    float bestd = INFINITY;
    unsigned int idx = 0;
#pragma unroll
    for (int s = 0; s < SEGS; ++s) {
        float2 v = wq[((size_t)s << 11) + n];
        if (v.x < bestd) { bestd = v.x; idx = __float_as_uint(v.y); }
    }

    float s = sl1(psrc[n * 3 + 0] - csrc[idx * 3 + 0])
            + sl1(psrc[n * 3 + 1] - csrc[idx * 3 + 1])
            + sl1(psrc[n * 3 + 2] - csrc[idx * 3 + 2]);

    __shared__ float wpart[4];
    for (int off = 32; off > 0; off >>= 1)
        s += __shfl_down(s, off, 64);
    if ((tid & 63) == 0) wpart[tid >> 6] = s;
    __syncthreads();
    if (tid == 0) {
        float tot = wpart[0] + wpart[1] + wpart[2] + wpart[3];
        atomicAdd(&out[0], W[set] * tot * (1.0f / (N_PTS * 3.0f * B_VAL)));
    }
}

extern "C" void kernel_launch(void* const* d_in, const int* in_sizes, int n_in,
                              void* d_out, int out_size, void* d_ws, size_t ws_size,
                              hipStream_t stream) {
    const float* X = (const float*)d_in[0];
    const float* T = (const float*)d_in[1];
    const float* W = (const float*)d_in[2];
    float* out = (float*)d_out;
    float2* ws = (float2*)d_ws;   // 32 * 16 * 2048 float2 = 8 MB

    chamfer_partial<<<dim3(SEGS, N_SETS, 2), BLOCK, 0, stream>>>(X, T, ws, out);
    finalize_kernel<<<dim3(N_PTS / BLOCK + 1, N_SETS, 2), BLOCK, 0, stream>>>(X, T, W, ws, out);
}